// Round 5
// baseline (589.355 us; speedup 1.0000x reference)
//
#include <hip/hip_runtime.h>
#include <math.h>

// B=8, N=4096, D=1024, E=512, C=4096.  M = 32768.
// Split-fp16 MFMA emulation of fp32 GEMM (a = h + l/2048, 3 MFMAs) for proj;
// hi-only fp16 pass for sim + deterministic margin rescue; contested rows
// recomputed exactly.
// R15: k_sim_h epilogue rewritten in u32 keys: key = (fkey(v) & ~0xFFF) |
//      (4095-col) — 12-bit col fits, key is self-tiebreaking (larger value,
//      then smaller col). Top-2 via max/med3-pattern, u32 butterfly, single
//      l15==0 store per (row,wn) into 2KB tables (was: u64 chains, 16x
//      redundant u64 stores, 32-entry strided scan -> the 524K bank
//      conflicts). Quantization bias <= 4096*ulp(5) ~ 0.002 per value ->
//      MARGIN 0.03 -> 0.034 keeps the rescue sound (contested +13%).
//      __launch_bounds__(256,3): VGPR 100 << 170 cap; 3x48KB LDS fits ->
//      scheduler may co-resident a 3rd block.
// Main loops of all kernels byte-identical to R14 (170us / 36% MfmaUtil
// baseline; 8-phase ports measured WORSE twice - abandoned).
//
// ws (MB): cn_h 0-4, cn_l 4-8, rpT_h 8-9, rpT_l 9-10, proj_h 10-42,
//          proj_l 42-74, pv1 74-78, pi1 78-82, pv2 82-86, rpv 86-90,
//          rpi 90-94, list 94-94.125, cnt @94.125

typedef _Float16 half8 __attribute__((ext_vector_type(8)));
typedef _Float16 half4 __attribute__((ext_vector_type(4)));
typedef float f32x4 __attribute__((ext_vector_type(4)));
typedef unsigned long long u64;
typedef unsigned int u32;

#define INV2048 (4.8828125e-4f)
#define MARGIN 0.034f

struct Split { _Float16 h, l; };

__device__ __forceinline__ Split split_f32(float v) {
    Split s;
    s.h = (_Float16)v;
    s.l = (_Float16)((v - (float)s.h) * 2048.0f);
    return s;
}

__device__ __forceinline__ void gl_lds16(const void* g, void* l) {
    __builtin_amdgcn_global_load_lds(
        (const __attribute__((address_space(1))) unsigned int*)g,
        (__attribute__((address_space(3))) unsigned int*)l, 16, 0, 0);
}

// monotone float->u32 key (finite inputs): order-preserving, key>0
__device__ __forceinline__ u32 fkey(float v) {
    u32 b = __float_as_uint(v);
    return b ^ ((u32)((int)b >> 31) | 0x80000000u);
}
__device__ __forceinline__ float fkeyinv(u32 u) {
    u32 m2 = (u32)((int)u >> 31);
    return __uint_as_float(u ^ ((~m2) | 0x80000000u));
}

// fused: blocks 0..127 transpose+split rp; blocks 128..4223 normalize+split cb
__global__ __launch_bounds__(256) void k_prep(const float* __restrict__ rp,
                                              _Float16* __restrict__ th,
                                              _Float16* __restrict__ tl,
                                              const float* __restrict__ cb,
                                              _Float16* __restrict__ ch,
                                              _Float16* __restrict__ cl,
                                              int* __restrict__ cnt) {
    const int t = threadIdx.x;
    if (blockIdx.x == 0 && t == 0) *cnt = 0;
    if (blockIdx.x < 128) {
        __shared__ float tile[64][65];
        const int k0 = (blockIdx.x & 15) * 64, n0 = (blockIdx.x >> 4) * 64;
        const int rr = t >> 6, cc = t & 63;
        #pragma unroll
        for (int i = 0; i < 16; ++i) {
            int r = i * 4 + rr;
            tile[r][cc] = rp[(size_t)(k0 + r) * 512 + n0 + cc];
        }
        __syncthreads();
        #pragma unroll
        for (int i = 0; i < 16; ++i) {
            int n = i * 4 + rr;
            Split s = split_f32(tile[cc][n]);
            size_t o = (size_t)(n0 + n) * 1024 + k0 + cc;
            th[o] = s.h;
            tl[o] = s.l;
        }
    } else {
        const int c = blockIdx.x - 128;
        const float* row = cb + (size_t)c * 512;
        float v0 = row[t];
        float v1 = row[t + 256];
        float ss = v0 * v0 + v1 * v1;
        #pragma unroll
        for (int o = 32; o > 0; o >>= 1) ss += __shfl_down(ss, o, 64);
        __shared__ float wsum[4];
        if ((t & 63) == 0) wsum[t >> 6] = ss;
        __syncthreads();
        float s = 1.0f / fmaxf(sqrtf(wsum[0] + wsum[1] + wsum[2] + wsum[3]), 1e-12f);
        Split s0 = split_f32(v0 * s);
        ch[(size_t)c * 512 + t] = s0.h;
        cl[(size_t)c * 512 + t] = s0.l;
        Split s1 = split_f32(v1 * s);
        ch[(size_t)c * 512 + t + 256] = s1.h;
        cl[(size_t)c * 512 + t + 256] = s1.l;
    }
}

// proj = x @ rp : M=32768, N=512, K=1024. split-fp16 3-MFMA (accurate).
// 1D grid, bijective XCD chunk swizzle (neutral-to-positive, kept).
__global__ __launch_bounds__(256, 2) void k_gemm1(const float* __restrict__ X,
                                                  const _Float16* __restrict__ Bh,
                                                  const _Float16* __restrict__ Bl,
                                                  _Float16* __restrict__ Ph,
                                                  _Float16* __restrict__ Pl) {
    __shared__ _Float16 sAh[128 * 64], sAl[128 * 64];   // 16 KB each
    __shared__ _Float16 sBh[128 * 64], sBl[128 * 64];   // 16 KB each
    const int t = threadIdx.x;
    const int bid = blockIdx.x;                 // 0..1023
    const int logical = (bid & 7) * 128 + (bid >> 3);   // bijective XCD chunking
    const int nb = logical & 3;   // 0..3
    const int mb = logical >> 2;  // 0..255
    const int lane = t & 63, w = t >> 6;
    const int quad = lane >> 4, l15 = lane & 15;
    const int wm = w >> 1, wn = w & 1;

    f32x4 acc[4][4], acc2[4][4];
    const f32x4 z = {0.f, 0.f, 0.f, 0.f};
    #pragma unroll
    for (int i = 0; i < 4; ++i)
        #pragma unroll
        for (int j = 0; j < 4; ++j) { acc[i][j] = z; acc2[i][j] = z; }

    const int srow8 = lane >> 3;
    const int sseg = (lane & 7) ^ srow8;
    const _Float16* gBh = Bh + (size_t)(nb * 128 + w * 32 + srow8) * 1024 + sseg * 8;
    const _Float16* gBl = Bl + (size_t)(nb * 128 + w * 32 + srow8) * 1024 + sseg * 8;

    const int xrow = t >> 1;
    const int xk8 = (t & 1) * 4;
    const float* gX = X + (size_t)(mb * 128 + xrow) * 1024 + xk8 * 8;
    _Float16* wAh = &sAh[xrow * 64];
    _Float16* wAl = &sAl[xrow * 64];
    const int xswz = xrow & 7;

    for (int ks = 0; ks < 16; ++ks) {
        const int ko = ks * 64;
        __syncthreads();
        #pragma unroll
        for (int c = 0; c < 4; ++c) {
            gl_lds16(gBh + ko + (size_t)(c * 8) * 1024, &sBh[(w * 32 + c * 8) * 64]);
            gl_lds16(gBl + ko + (size_t)(c * 8) * 1024, &sBl[(w * 32 + c * 8) * 64]);
        }
        #pragma unroll
        for (int j = 0; j < 4; ++j) {
            float4 v0 = *(const float4*)(gX + ko + j * 8);
            float4 v1 = *(const float4*)(gX + ko + j * 8 + 4);
            Split s0 = split_f32(v0.x), s1 = split_f32(v0.y);
            Split s2 = split_f32(v0.z), s3 = split_f32(v0.w);
            Split s4 = split_f32(v1.x), s5 = split_f32(v1.y);
            Split s6 = split_f32(v1.z), s7 = split_f32(v1.w);
            half8 hv, lv;
            hv[0] = s0.h; hv[1] = s1.h; hv[2] = s2.h; hv[3] = s3.h;
            hv[4] = s4.h; hv[5] = s5.h; hv[6] = s6.h; hv[7] = s7.h;
            lv[0] = s0.l; lv[1] = s1.l; lv[2] = s2.l; lv[3] = s3.l;
            lv[4] = s4.l; lv[5] = s5.l; lv[6] = s6.l; lv[7] = s7.l;
            const int slot = ((xk8 + j) ^ xswz) * 8;
            *(half8*)&wAh[slot] = hv;
            *(half8*)&wAl[slot] = lv;
        }
        __syncthreads();
        #pragma unroll
        for (int phase = 0; phase < 2; ++phase) {
            const int slot = (((phase << 2) | quad) ^ (l15 & 7)) * 8;
            half8 ah[4], al[4], bh[4], bl[4];
            #pragma unroll
            for (int i = 0; i < 4; ++i) {
                ah[i] = *(const half8*)&sAh[(wm * 64 + i * 16 + l15) * 64 + slot];
                al[i] = *(const half8*)&sAl[(wm * 64 + i * 16 + l15) * 64 + slot];
                bh[i] = *(const half8*)&sBh[(wn * 64 + i * 16 + l15) * 64 + slot];
                bl[i] = *(const half8*)&sBl[(wn * 64 + i * 16 + l15) * 64 + slot];
            }
            #pragma unroll
            for (int mi = 0; mi < 4; ++mi)
                #pragma unroll
                for (int ni = 0; ni < 4; ++ni) {
                    acc[mi][ni]  = __builtin_amdgcn_mfma_f32_16x16x32_f16(ah[mi], bh[ni], acc[mi][ni], 0, 0, 0);
                    acc2[mi][ni] = __builtin_amdgcn_mfma_f32_16x16x32_f16(ah[mi], bl[ni], acc2[mi][ni], 0, 0, 0);
                    acc2[mi][ni] = __builtin_amdgcn_mfma_f32_16x16x32_f16(al[mi], bh[ni], acc2[mi][ni], 0, 0, 0);
                }
        }
    }
    #pragma unroll
    for (int mi = 0; mi < 4; ++mi)
        #pragma unroll
        for (int r = 0; r < 4; ++r) {
            int row = mb * 128 + wm * 64 + mi * 16 + quad * 4 + r;
            #pragma unroll
            for (int ni = 0; ni < 4; ++ni) {
                int col = nb * 128 + wn * 64 + ni * 16 + l15;
                float v = acc[mi][ni][r] + acc2[mi][ni][r] * INV2048;
                Split s = split_f32(v);
                Ph[(size_t)row * 512 + col] = s.h;
                Pl[(size_t)row * 512 + col] = s.l;
            }
        }
}

// PASS 1: hi-only sim. 128m x 256c tile, BK=64, 8 K-iters, 2 barriers/iter.
// Swizzle: LDS slot s (16B units, 8/row) of row r holds global seg s^(r&7).
// R15 epilogue: u32 keys (20-bit value | 12-bit ~col), med3-pattern top-2.
__global__ __launch_bounds__(256, 3) void k_sim_h(const _Float16* __restrict__ Ah,
                                                  const _Float16* __restrict__ Bh,
                                                  float* __restrict__ pv1,
                                                  int* __restrict__ pi1,
                                                  float* __restrict__ pv2) {
    __shared__ __align__(16) long long smem64[6144];   // 48 KB
    _Float16* sA = (_Float16*)smem64;                  // [128][64] halfs, 16 KB
    _Float16* sB = sA + 128 * 64;                      // [256][64] halfs, 32 KB
    u32* ek1 = (u32*)smem64;                           // [128][2] u32, 1 KB
    u32* ek2 = ek1 + 256;                              // [128][2] u32, 1 KB
    const int t = threadIdx.x;
    const int cbk = blockIdx.x;  // 0..15 (256-wide c-tiles)
    const int mb = blockIdx.y;   // 0..255
    const int lane = t & 63, w = t >> 6;
    const int quad = lane >> 4, l15 = lane & 15;
    const int wm = w >> 1, wn = w & 1;

    f32x4 acc[4][8];
    const f32x4 z = {0.f, 0.f, 0.f, 0.f};
    #pragma unroll
    for (int i = 0; i < 4; ++i)
        #pragma unroll
        for (int j = 0; j < 8; ++j) acc[i][j] = z;

    const int srow8 = lane >> 3;
    const int sseg = (lane & 7) ^ srow8;
    const _Float16* gA = Ah + (size_t)(mb * 128 + w * 32 + srow8) * 512 + sseg * 8;
    const _Float16* gB = Bh + (size_t)(cbk * 256 + w * 64 + srow8) * 512 + sseg * 8;

    for (int ks = 0; ks < 8; ++ks) {
        const int ko = ks * 64;
        __syncthreads();
        #pragma unroll
        for (int c = 0; c < 4; ++c)
            gl_lds16(gA + ko + (size_t)(c * 8) * 512, &sA[(w * 32 + c * 8) * 64]);
        #pragma unroll
        for (int c = 0; c < 8; ++c)
            gl_lds16(gB + ko + (size_t)(c * 8) * 512, &sB[(w * 64 + c * 8) * 64]);
        __syncthreads();
        #pragma unroll
        for (int phase = 0; phase < 2; ++phase) {
            const int slot = (((phase << 2) | quad) ^ (l15 & 7)) * 8;
            half8 a[4], b[8];
            #pragma unroll
            for (int i = 0; i < 4; ++i)
                a[i] = *(const half8*)&sA[(wm * 64 + i * 16 + l15) * 64 + slot];
            #pragma unroll
            for (int j = 0; j < 8; ++j)
                b[j] = *(const half8*)&sB[(wn * 128 + j * 16 + l15) * 64 + slot];
            #pragma unroll
            for (int mi = 0; mi < 4; ++mi)
                #pragma unroll
                for (int ni = 0; ni < 8; ++ni)
                    acc[mi][ni] = __builtin_amdgcn_mfma_f32_16x16x32_f16(a[mi], b[ni], acc[mi][ni], 0, 0, 0);
        }
    }

    __syncthreads();   // staging dead; reuse LDS as epilogue table
    // key = (fkey(v) & ~0xFFF) | (4095 - col): one u32, self-tiebreaking
    // (bigger value wins; on truncated-equal values, smaller col wins).
    const u32 colbase = 4095u - (u32)(cbk * 256 + wn * 128 + l15);
    #pragma unroll
    for (int mi = 0; mi < 4; ++mi)
        #pragma unroll
        for (int r = 0; r < 4; ++r) {
            int row = wm * 64 + mi * 16 + quad * 4 + r;
            u32 p1 = 0, p2 = 0;
            #pragma unroll
            for (int ni = 0; ni < 8; ++ni) {
                u32 k = (fkey(acc[mi][ni][r]) & 0xFFFFF000u) | (colbase - (u32)(ni * 16));
                u32 old1 = p1;
                u32 mn = old1 < k ? old1 : k;   // p2' = med3(p1, p2, k)
                p1 = old1 > k ? old1 : k;
                p2 = p2 > mn ? p2 : mn;
            }
            #pragma unroll
            for (int m = 1; m < 16; m <<= 1) {  // merge 16 lanes (same row)
                u32 q1 = __shfl_xor(p1, m, 64);
                u32 q2 = __shfl_xor(p2, m, 64);
                u32 m2 = p2 > q2 ? p2 : q2;
                u32 mn = p1 < q1 ? p1 : q1;
                p1 = p1 > q1 ? p1 : q1;
                p2 = m2 > mn ? m2 : mn;
            }
            if (l15 == 0) {
                ek1[row * 2 + wn] = p1;
                ek2[row * 2 + wn] = p2;
            }
        }
    __syncthreads();
    if (t < 128) {
        u32 a1 = ek1[t * 2], b1 = ek1[t * 2 + 1];
        u32 a2 = ek2[t * 2], b2 = ek2[t * 2 + 1];
        u32 top1 = a1 > b1 ? a1 : b1;
        u32 mn = a1 < b1 ? a1 : b1;
        u32 m2 = a2 > b2 ? a2 : b2;
        u32 top2 = m2 > mn ? m2 : mn;
        size_t o = (size_t)(mb * 128 + t) * 16 + cbk;
        pv1[o] = fkeyinv(top1 & 0xFFFFF000u);
        pi1[o] = (int)(4095u - (top1 & 0xFFFu));
        pv2[o] = fkeyinv(top2 & 0xFFFFF000u);
    }
}

// reduce 16 c-tile partials; commit confident rows, queue contested ones
__global__ __launch_bounds__(256) void k_flag(const float* __restrict__ pv1,
                                              const int* __restrict__ pi1,
                                              const float* __restrict__ pv2,
                                              int* __restrict__ out,
                                              int* __restrict__ list,
                                              int* __restrict__ cnt) {
    int r = blockIdx.x * 256 + threadIdx.x;
    if (r >= 32768) return;
    size_t base = (size_t)r * 16;
    float v1 = pv1[base], v2 = pv2[base];
    int i1 = pi1[base];
    #pragma unroll
    for (int j = 1; j < 16; ++j) {
        float ov1 = pv1[base + j], ov2 = pv2[base + j];
        int oi1 = pi1[base + j];
        if (ov1 > v1 || (ov1 == v1 && oi1 < i1)) { v2 = fmaxf(v1, ov2); v1 = ov1; i1 = oi1; }
        else v2 = fmaxf(v2, ov1);
    }
    out[r] = i1;
    if (v1 - v2 < MARGIN) {
        int p = atomicAdd(cnt, 1);
        list[p] = r;
    }
}

// PASS 2: exact 3-MFMA sim on gathered contested rows
__global__ __launch_bounds__(256, 2) void k_sim_fix(const _Float16* __restrict__ Ah,
                                                    const _Float16* __restrict__ Al,
                                                    const _Float16* __restrict__ Bh,
                                                    const _Float16* __restrict__ Bl,
                                                    const int* __restrict__ list,
                                                    const int* __restrict__ cnt,
                                                    float* __restrict__ rpv,
                                                    int* __restrict__ rpi) {
    __shared__ _Float16 sAh[128 * 32], sAl[128 * 32], sBh[128 * 32], sBl[128 * 32];
    __shared__ int rowidx[128];
    __shared__ float pvs[128][2];
    __shared__ int   pis[128][2];
    const int count = *cnt;
    const int t = threadIdx.x;
    const int cbk = blockIdx.x;  // 0..31
    const int lane = t & 63, w = t >> 6;
    const int quad = lane >> 4, l15 = lane & 15;
    const int wm = w >> 1, wn = w & 1;

    const int srow = w * 32 + (lane >> 2);
    const int kcol = (lane & 3) * 8;
    const _Float16* gBh = Bh + (size_t)(cbk * 128 + srow) * 512 + kcol;
    const _Float16* gBl = Bl + (size_t)(cbk * 128 + srow) * 512 + kcol;

    for (int g = blockIdx.y; g * 128 < count; g += gridDim.y) {
        __syncthreads();
        if (t < 128) {
            int p = g * 128 + t;
            rowidx[t] = (p < count) ? list[p] : list[0];
        }
        __syncthreads();

        f32x4 acc[4][4], acc2[4][4];
        const f32x4 z = {0.f, 0.f, 0.f, 0.f};
        #pragma unroll
        for (int i = 0; i < 4; ++i)
            #pragma unroll
            for (int j = 0; j < 4; ++j) { acc[i][j] = z; acc2[i][j] = z; }

        for (int ks = 0; ks < 16; ++ks) {
            const int ko = ks * 32;
            __syncthreads();
            gl_lds16(gBh + ko, &sBh[w * 1024]);
            gl_lds16(gBh + ko + (size_t)16 * 512, &sBh[w * 1024 + 512]);
            gl_lds16(gBl + ko, &sBl[w * 1024]);
            gl_lds16(gBl + ko + (size_t)16 * 512, &sBl[w * 1024 + 512]);
            #pragma unroll
            for (int i = 0; i < 2; ++i) {
                int idx = i * 256 + t;          // 0..511
                int row = idx >> 2, seg = (idx & 3) * 8;
                size_t src = (size_t)rowidx[row] * 512 + ko + seg;
                *(half8*)&sAh[row * 32 + seg] = *(const half8*)(Ah + src);
                *(half8*)&sAl[row * 32 + seg] = *(const half8*)(Al + src);
            }
            __syncthreads();
            half8 ah[4], al[4], bh[4], bl[4];
            #pragma unroll
            for (int i = 0; i < 4; ++i) {
                ah[i] = *(const half8*)&sAh[(wm * 64 + i * 16 + l15) * 32 + quad * 8];
                al[i] = *(const half8*)&sAl[(wm * 64 + i * 16 + l15) * 32 + quad * 8];
                bh[i] = *(const half8*)&sBh[(wn * 64 + i * 16 + l15) * 32 + quad * 8];
                bl[i] = *(const half8*)&sBl[(wn * 64 + i * 16 + l15) * 32 + quad * 8];
            }
            #pragma unroll
            for (int mi = 0; mi < 4; ++mi)
                #pragma unroll
                for (int ni = 0; ni < 4; ++ni) {
                    acc[mi][ni]  = __builtin_amdgcn_mfma_f32_16x16x32_f16(ah[mi], bh[ni], acc[mi][ni], 0, 0, 0);
                    acc2[mi][ni] = __builtin_amdgcn_mfma_f32_16x16x32_f16(ah[mi], bl[ni], acc2[mi][ni], 0, 0, 0);
                    acc2[mi][ni] = __builtin_amdgcn_mfma_f32_16x16x32_f16(al[mi], bh[ni], acc2[mi][ni], 0, 0, 0);
                }
        }

        #pragma unroll
        for (int mi = 0; mi < 4; ++mi)
            #pragma unroll
            for (int r = 0; r < 4; ++r) {
                float bv = -INFINITY;
                int bi = 0x7fffffff;
                #pragma unroll
                for (int ni = 0; ni < 4; ++ni) {
                    float v = acc[mi][ni][r] + acc2[mi][ni][r] * INV2048;
                    int col = cbk * 128 + wn * 64 + ni * 16 + l15;
                    if (v > bv || (v == bv && col < bi)) { bv = v; bi = col; }
                }
                #pragma unroll
                for (int o = 1; o < 16; o <<= 1) {
                    float ov = __shfl_xor(bv, o, 64);
                    int oi = __shfl_xor(bi, o, 64);
                    if (ov > bv || (ov == bv && oi < bi)) { bv = ov; bi = oi; }
                }
                if (l15 == 0) {
                    int row = wm * 64 + mi * 16 + quad * 4 + r;
                    pvs[row][wn] = bv; pis[row][wn] = bi;
                }
            }
        __syncthreads();
        if (t < 128 && g * 128 + t < count) {
            float v0 = pvs[t][0], v1 = pvs[t][1];
            int i0 = pis[t][0], i1 = pis[t][1];
            bool sw = (v1 > v0) || (v1 == v0 && i1 < i0);
            size_t o = (size_t)(g * 128 + t) * 32 + cbk;
            rpv[o] = sw ? v1 : v0;
            rpi[o] = sw ? i1 : i0;
        }
    }
}

__global__ __launch_bounds__(256) void k_fix(const float* __restrict__ rpv,
                                             const int* __restrict__ rpi,
                                             const int* __restrict__ list,
                                             const int* __restrict__ cnt,
                                             int* __restrict__ out) {
    int p = blockIdx.x * 256 + threadIdx.x;
    if (p >= *cnt) return;
    size_t base = (size_t)p * 32;
    float bv = -INFINITY;
    int bi = 0x7fffffff;
    #pragma unroll
    for (int j = 0; j < 32; ++j) {
        float v = rpv[base + j];
        int ci = rpi[base + j];
        if (v > bv || (v == bv && ci < bi)) { bv = v; bi = ci; }
    }
    out[list[p]] = bi;
}

extern "C" void kernel_launch(void* const* d_in, const int* in_sizes, int n_in,
                              void* d_out, int out_size, void* d_ws, size_t ws_size,
                              hipStream_t stream) {
    const float* x  = (const float*)d_in[0];   // [8,4096,1024]
    const float* rp = (const float*)d_in[1];   // [1024,512]
    const float* cb = (const float*)d_in[2];   // [4096,512]
    int* out = (int*)d_out;                    // [32768] int32

    char* ws = (char*)d_ws;
    _Float16* cn_h   = (_Float16*)(ws);
    _Float16* cn_l   = (_Float16*)(ws + ((size_t)4 << 20));
    _Float16* rpT_h  = (_Float16*)(ws + ((size_t)8 << 20));
    _Float16* rpT_l  = (_Float16*)(ws + ((size_t)9 << 20));
    _Float16* proj_h = (_Float16*)(ws + ((size_t)10 << 20));
    _Float16* proj_l = (_Float16*)(ws + ((size_t)42 << 20));
    float*    pv1    = (float*)   (ws + ((size_t)74 << 20));
    int*      pi1    = (int*)     (ws + ((size_t)78 << 20));
    float*    pv2    = (float*)   (ws + ((size_t)82 << 20));
    float*    rpv    = (float*)   (ws + ((size_t)86 << 20));
    int*      rpi    = (int*)     (ws + ((size_t)90 << 20));
    int*      list   = (int*)     (ws + ((size_t)94 << 20));
    int*      cnt    = (int*)     (ws + ((size_t)94 << 20) + (128 << 10));

    k_prep<<<4224, 256, 0, stream>>>(rp, rpT_h, rpT_l, cb, cn_h, cn_l, cnt);
    k_gemm1<<<1024, 256, 0, stream>>>(x, rpT_h, rpT_l, proj_h, proj_l);
    k_sim_h<<<dim3(16, 256), 256, 0, stream>>>(proj_h, cn_h, pv1, pi1, pv2);
    k_flag<<<128, 256, 0, stream>>>(pv1, pi1, pv2, out, list, cnt);
    k_sim_fix<<<dim3(32, 32), 256, 0, stream>>>(proj_h, proj_l, cn_h, cn_l, list, cnt, rpv, rpi);
    k_fix<<<128, 256, 0, stream>>>(rpv, rpi, list, cnt, out);
}

// Round 8
// 525.625 us; speedup vs baseline: 1.1212x; 1.1212x over previous
//
#include <hip/hip_runtime.h>
#include <math.h>

// B=8, N=4096, D=1024, E=512, C=4096.  M = 32768.
// Split-fp16 MFMA emulation of fp32 GEMM (a = h + l/2048, 3 MFMAs) for proj;
// hi-only fp16 pass for sim + deterministic margin rescue; contested rows
// recomputed exactly.
// R18 = R16 resubmit #2 (R16/R17 both hit GPUAcquisitionTimeout, never ran).
// R16: keep R15's u32-key epilogue (bank conflicts 524K->0, VALU -14pts),
//      revert launch_bounds to (256,2) (3rd block/CU was net-negative:
//      FETCH +33MB, WRITE 48->214MB cache thrash, dur 170->229), and fix
//      the partial-table layout: pv1/pi1/pv2 now [cbk][row] (o = cbk*32768
//      + row) so each block writes contiguous full 64B lines instead of
//      16 XCDs doing 4B RMWs into the same line (the 48MB WRITE_SIZE for
//      6MB payload in R14). k_flag reads [j*32768 + r], coalesced.
// Main loops byte-identical to R14 (170us / 36% MfmaUtil baseline).
//
// ws (MB): cn_h 0-4, cn_l 4-8, rpT_h 8-9, rpT_l 9-10, proj_h 10-42,
//          proj_l 42-74, pv1 74-78, pi1 78-82, pv2 82-86, rpv 86-90,
//          rpi 90-94, list 94-94.125, cnt @94.125

typedef _Float16 half8 __attribute__((ext_vector_type(8)));
typedef _Float16 half4 __attribute__((ext_vector_type(4)));
typedef float f32x4 __attribute__((ext_vector_type(4)));
typedef unsigned long long u64;
typedef unsigned int u32;

#define INV2048 (4.8828125e-4f)
#define MARGIN 0.034f

struct Split { _Float16 h, l; };

__device__ __forceinline__ Split split_f32(float v) {
    Split s;
    s.h = (_Float16)v;
    s.l = (_Float16)((v - (float)s.h) * 2048.0f);
    return s;
}

__device__ __forceinline__ void gl_lds16(const void* g, void* l) {
    __builtin_amdgcn_global_load_lds(
        (const __attribute__((address_space(1))) unsigned int*)g,
        (__attribute__((address_space(3))) unsigned int*)l, 16, 0, 0);
}

// monotone float->u32 key (finite inputs): order-preserving, key>0
__device__ __forceinline__ u32 fkey(float v) {
    u32 b = __float_as_uint(v);
    return b ^ ((u32)((int)b >> 31) | 0x80000000u);
}
__device__ __forceinline__ float fkeyinv(u32 u) {
    u32 m2 = (u32)((int)u >> 31);
    return __uint_as_float(u ^ ((~m2) | 0x80000000u));
}

// fused: blocks 0..127 transpose+split rp; blocks 128..4223 normalize+split cb
__global__ __launch_bounds__(256) void k_prep(const float* __restrict__ rp,
                                              _Float16* __restrict__ th,
                                              _Float16* __restrict__ tl,
                                              const float* __restrict__ cb,
                                              _Float16* __restrict__ ch,
                                              _Float16* __restrict__ cl,
                                              int* __restrict__ cnt) {
    const int t = threadIdx.x;
    if (blockIdx.x == 0 && t == 0) *cnt = 0;
    if (blockIdx.x < 128) {
        __shared__ float tile[64][65];
        const int k0 = (blockIdx.x & 15) * 64, n0 = (blockIdx.x >> 4) * 64;
        const int rr = t >> 6, cc = t & 63;
        #pragma unroll
        for (int i = 0; i < 16; ++i) {
            int r = i * 4 + rr;
            tile[r][cc] = rp[(size_t)(k0 + r) * 512 + n0 + cc];
        }
        __syncthreads();
        #pragma unroll
        for (int i = 0; i < 16; ++i) {
            int n = i * 4 + rr;
            Split s = split_f32(tile[cc][n]);
            size_t o = (size_t)(n0 + n) * 1024 + k0 + cc;
            th[o] = s.h;
            tl[o] = s.l;
        }
    } else {
        const int c = blockIdx.x - 128;
        const float* row = cb + (size_t)c * 512;
        float v0 = row[t];
        float v1 = row[t + 256];
        float ss = v0 * v0 + v1 * v1;
        #pragma unroll
        for (int o = 32; o > 0; o >>= 1) ss += __shfl_down(ss, o, 64);
        __shared__ float wsum[4];
        if ((t & 63) == 0) wsum[t >> 6] = ss;
        __syncthreads();
        float s = 1.0f / fmaxf(sqrtf(wsum[0] + wsum[1] + wsum[2] + wsum[3]), 1e-12f);
        Split s0 = split_f32(v0 * s);
        ch[(size_t)c * 512 + t] = s0.h;
        cl[(size_t)c * 512 + t] = s0.l;
        Split s1 = split_f32(v1 * s);
        ch[(size_t)c * 512 + t + 256] = s1.h;
        cl[(size_t)c * 512 + t + 256] = s1.l;
    }
}

// proj = x @ rp : M=32768, N=512, K=1024. split-fp16 3-MFMA (accurate).
// 1D grid, bijective XCD chunk swizzle (neutral-to-positive, kept).
__global__ __launch_bounds__(256, 2) void k_gemm1(const float* __restrict__ X,
                                                  const _Float16* __restrict__ Bh,
                                                  const _Float16* __restrict__ Bl,
                                                  _Float16* __restrict__ Ph,
                                                  _Float16* __restrict__ Pl) {
    __shared__ _Float16 sAh[128 * 64], sAl[128 * 64];   // 16 KB each
    __shared__ _Float16 sBh[128 * 64], sBl[128 * 64];   // 16 KB each
    const int t = threadIdx.x;
    const int bid = blockIdx.x;                 // 0..1023
    const int logical = (bid & 7) * 128 + (bid >> 3);   // bijective XCD chunking
    const int nb = logical & 3;   // 0..3
    const int mb = logical >> 2;  // 0..255
    const int lane = t & 63, w = t >> 6;
    const int quad = lane >> 4, l15 = lane & 15;
    const int wm = w >> 1, wn = w & 1;

    f32x4 acc[4][4], acc2[4][4];
    const f32x4 z = {0.f, 0.f, 0.f, 0.f};
    #pragma unroll
    for (int i = 0; i < 4; ++i)
        #pragma unroll
        for (int j = 0; j < 4; ++j) { acc[i][j] = z; acc2[i][j] = z; }

    const int srow8 = lane >> 3;
    const int sseg = (lane & 7) ^ srow8;
    const _Float16* gBh = Bh + (size_t)(nb * 128 + w * 32 + srow8) * 1024 + sseg * 8;
    const _Float16* gBl = Bl + (size_t)(nb * 128 + w * 32 + srow8) * 1024 + sseg * 8;

    const int xrow = t >> 1;
    const int xk8 = (t & 1) * 4;
    const float* gX = X + (size_t)(mb * 128 + xrow) * 1024 + xk8 * 8;
    _Float16* wAh = &sAh[xrow * 64];
    _Float16* wAl = &sAl[xrow * 64];
    const int xswz = xrow & 7;

    for (int ks = 0; ks < 16; ++ks) {
        const int ko = ks * 64;
        __syncthreads();
        #pragma unroll
        for (int c = 0; c < 4; ++c) {
            gl_lds16(gBh + ko + (size_t)(c * 8) * 1024, &sBh[(w * 32 + c * 8) * 64]);
            gl_lds16(gBl + ko + (size_t)(c * 8) * 1024, &sBl[(w * 32 + c * 8) * 64]);
        }
        #pragma unroll
        for (int j = 0; j < 4; ++j) {
            float4 v0 = *(const float4*)(gX + ko + j * 8);
            float4 v1 = *(const float4*)(gX + ko + j * 8 + 4);
            Split s0 = split_f32(v0.x), s1 = split_f32(v0.y);
            Split s2 = split_f32(v0.z), s3 = split_f32(v0.w);
            Split s4 = split_f32(v1.x), s5 = split_f32(v1.y);
            Split s6 = split_f32(v1.z), s7 = split_f32(v1.w);
            half8 hv, lv;
            hv[0] = s0.h; hv[1] = s1.h; hv[2] = s2.h; hv[3] = s3.h;
            hv[4] = s4.h; hv[5] = s5.h; hv[6] = s6.h; hv[7] = s7.h;
            lv[0] = s0.l; lv[1] = s1.l; lv[2] = s2.l; lv[3] = s3.l;
            lv[4] = s4.l; lv[5] = s5.l; lv[6] = s6.l; lv[7] = s7.l;
            const int slot = ((xk8 + j) ^ xswz) * 8;
            *(half8*)&wAh[slot] = hv;
            *(half8*)&wAl[slot] = lv;
        }
        __syncthreads();
        #pragma unroll
        for (int phase = 0; phase < 2; ++phase) {
            const int slot = (((phase << 2) | quad) ^ (l15 & 7)) * 8;
            half8 ah[4], al[4], bh[4], bl[4];
            #pragma unroll
            for (int i = 0; i < 4; ++i) {
                ah[i] = *(const half8*)&sAh[(wm * 64 + i * 16 + l15) * 64 + slot];
                al[i] = *(const half8*)&sAl[(wm * 64 + i * 16 + l15) * 64 + slot];
                bh[i] = *(const half8*)&sBh[(wn * 64 + i * 16 + l15) * 64 + slot];
                bl[i] = *(const half8*)&sBl[(wn * 64 + i * 16 + l15) * 64 + slot];
            }
            #pragma unroll
            for (int mi = 0; mi < 4; ++mi)
                #pragma unroll
                for (int ni = 0; ni < 4; ++ni) {
                    acc[mi][ni]  = __builtin_amdgcn_mfma_f32_16x16x32_f16(ah[mi], bh[ni], acc[mi][ni], 0, 0, 0);
                    acc2[mi][ni] = __builtin_amdgcn_mfma_f32_16x16x32_f16(ah[mi], bl[ni], acc2[mi][ni], 0, 0, 0);
                    acc2[mi][ni] = __builtin_amdgcn_mfma_f32_16x16x32_f16(al[mi], bh[ni], acc2[mi][ni], 0, 0, 0);
                }
        }
    }
    #pragma unroll
    for (int mi = 0; mi < 4; ++mi)
        #pragma unroll
        for (int r = 0; r < 4; ++r) {
            int row = mb * 128 + wm * 64 + mi * 16 + quad * 4 + r;
            #pragma unroll
            for (int ni = 0; ni < 4; ++ni) {
                int col = nb * 128 + wn * 64 + ni * 16 + l15;
                float v = acc[mi][ni][r] + acc2[mi][ni][r] * INV2048;
                Split s = split_f32(v);
                Ph[(size_t)row * 512 + col] = s.h;
                Pl[(size_t)row * 512 + col] = s.l;
            }
        }
}

// PASS 1: hi-only sim. 128m x 256c tile, BK=64, 8 K-iters, 2 barriers/iter.
// Swizzle: LDS slot s (16B units, 8/row) of row r holds global seg s^(r&7).
// u32-key epilogue; partials stored [cbk][row] (full-line coalesced writes).
__global__ __launch_bounds__(256, 2) void k_sim_h(const _Float16* __restrict__ Ah,
                                                  const _Float16* __restrict__ Bh,
                                                  float* __restrict__ pv1,
                                                  int* __restrict__ pi1,
                                                  float* __restrict__ pv2) {
    __shared__ __align__(16) long long smem64[6144];   // 48 KB
    _Float16* sA = (_Float16*)smem64;                  // [128][64] halfs, 16 KB
    _Float16* sB = sA + 128 * 64;                      // [256][64] halfs, 32 KB
    u32* ek1 = (u32*)smem64;                           // [128][2] u32, 1 KB
    u32* ek2 = ek1 + 256;                              // [128][2] u32, 1 KB
    const int t = threadIdx.x;
    const int cbk = blockIdx.x;  // 0..15 (256-wide c-tiles)
    const int mb = blockIdx.y;   // 0..255
    const int lane = t & 63, w = t >> 6;
    const int quad = lane >> 4, l15 = lane & 15;
    const int wm = w >> 1, wn = w & 1;

    f32x4 acc[4][8];
    const f32x4 z = {0.f, 0.f, 0.f, 0.f};
    #pragma unroll
    for (int i = 0; i < 4; ++i)
        #pragma unroll
        for (int j = 0; j < 8; ++j) acc[i][j] = z;

    const int srow8 = lane >> 3;
    const int sseg = (lane & 7) ^ srow8;
    const _Float16* gA = Ah + (size_t)(mb * 128 + w * 32 + srow8) * 512 + sseg * 8;
    const _Float16* gB = Bh + (size_t)(cbk * 256 + w * 64 + srow8) * 512 + sseg * 8;

    for (int ks = 0; ks < 8; ++ks) {
        const int ko = ks * 64;
        __syncthreads();
        #pragma unroll
        for (int c = 0; c < 4; ++c)
            gl_lds16(gA + ko + (size_t)(c * 8) * 512, &sA[(w * 32 + c * 8) * 64]);
        #pragma unroll
        for (int c = 0; c < 8; ++c)
            gl_lds16(gB + ko + (size_t)(c * 8) * 512, &sB[(w * 64 + c * 8) * 64]);
        __syncthreads();
        #pragma unroll
        for (int phase = 0; phase < 2; ++phase) {
            const int slot = (((phase << 2) | quad) ^ (l15 & 7)) * 8;
            half8 a[4], b[8];
            #pragma unroll
            for (int i = 0; i < 4; ++i)
                a[i] = *(const half8*)&sA[(wm * 64 + i * 16 + l15) * 64 + slot];
            #pragma unroll
            for (int j = 0; j < 8; ++j)
                b[j] = *(const half8*)&sB[(wn * 128 + j * 16 + l15) * 64 + slot];
            #pragma unroll
            for (int mi = 0; mi < 4; ++mi)
                #pragma unroll
                for (int ni = 0; ni < 8; ++ni)
                    acc[mi][ni] = __builtin_amdgcn_mfma_f32_16x16x32_f16(a[mi], b[ni], acc[mi][ni], 0, 0, 0);
        }
    }

    __syncthreads();   // staging dead; reuse LDS as epilogue table
    // key = (fkey(v) & ~0xFFF) | (4095 - col): one u32, self-tiebreaking
    // (bigger value wins; on truncated-equal values, smaller col wins).
    const u32 colbase = 4095u - (u32)(cbk * 256 + wn * 128 + l15);
    #pragma unroll
    for (int mi = 0; mi < 4; ++mi)
        #pragma unroll
        for (int r = 0; r < 4; ++r) {
            int row = wm * 64 + mi * 16 + quad * 4 + r;
            u32 p1 = 0, p2 = 0;
            #pragma unroll
            for (int ni = 0; ni < 8; ++ni) {
                u32 k = (fkey(acc[mi][ni][r]) & 0xFFFFF000u) | (colbase - (u32)(ni * 16));
                u32 old1 = p1;
                u32 mn = old1 < k ? old1 : k;   // p2' = med3(p1, p2, k)
                p1 = old1 > k ? old1 : k;
                p2 = p2 > mn ? p2 : mn;
            }
            #pragma unroll
            for (int m = 1; m < 16; m <<= 1) {  // merge 16 lanes (same row)
                u32 q1 = __shfl_xor(p1, m, 64);
                u32 q2 = __shfl_xor(p2, m, 64);
                u32 m2 = p2 > q2 ? p2 : q2;
                u32 mn = p1 < q1 ? p1 : q1;
                p1 = p1 > q1 ? p1 : q1;
                p2 = m2 > mn ? m2 : mn;
            }
            if (l15 == 0) {
                ek1[row * 2 + wn] = p1;
                ek2[row * 2 + wn] = p2;
            }
        }
    __syncthreads();
    if (t < 128) {
        u32 a1 = ek1[t * 2], b1 = ek1[t * 2 + 1];
        u32 a2 = ek2[t * 2], b2 = ek2[t * 2 + 1];
        u32 top1 = a1 > b1 ? a1 : b1;
        u32 mn = a1 < b1 ? a1 : b1;
        u32 m2 = a2 > b2 ? a2 : b2;
        u32 top2 = m2 > mn ? m2 : mn;
        // [cbk][row] layout: contiguous full-line writes per block
        size_t o = (size_t)cbk * 32768 + (size_t)(mb * 128 + t);
        pv1[o] = fkeyinv(top1 & 0xFFFFF000u);
        pi1[o] = (int)(4095u - (top1 & 0xFFFu));
        pv2[o] = fkeyinv(top2 & 0xFFFFF000u);
    }
}

// reduce 16 c-tile partials; commit confident rows, queue contested ones
// partials are [cbk][row]: read pv[j*32768 + r] (coalesced per j)
__global__ __launch_bounds__(256) void k_flag(const float* __restrict__ pv1,
                                              const int* __restrict__ pi1,
                                              const float* __restrict__ pv2,
                                              int* __restrict__ out,
                                              int* __restrict__ list,
                                              int* __restrict__ cnt) {
    int r = blockIdx.x * 256 + threadIdx.x;
    if (r >= 32768) return;
    float v1 = pv1[r], v2 = pv2[r];
    int i1 = pi1[r];
    #pragma unroll
    for (int j = 1; j < 16; ++j) {
        float ov1 = pv1[(size_t)j * 32768 + r], ov2 = pv2[(size_t)j * 32768 + r];
        int oi1 = pi1[(size_t)j * 32768 + r];
        if (ov1 > v1 || (ov1 == v1 && oi1 < i1)) { v2 = fmaxf(v1, ov2); v1 = ov1; i1 = oi1; }
        else v2 = fmaxf(v2, ov1);
    }
    out[r] = i1;
    if (v1 - v2 < MARGIN) {
        int p = atomicAdd(cnt, 1);
        list[p] = r;
    }
}

// PASS 2: exact 3-MFMA sim on gathered contested rows
__global__ __launch_bounds__(256, 2) void k_sim_fix(const _Float16* __restrict__ Ah,
                                                    const _Float16* __restrict__ Al,
                                                    const _Float16* __restrict__ Bh,
                                                    const _Float16* __restrict__ Bl,
                                                    const int* __restrict__ list,
                                                    const int* __restrict__ cnt,
                                                    float* __restrict__ rpv,
                                                    int* __restrict__ rpi) {
    __shared__ _Float16 sAh[128 * 32], sAl[128 * 32], sBh[128 * 32], sBl[128 * 32];
    __shared__ int rowidx[128];
    __shared__ float pvs[128][2];
    __shared__ int   pis[128][2];
    const int count = *cnt;
    const int t = threadIdx.x;
    const int cbk = blockIdx.x;  // 0..31
    const int lane = t & 63, w = t >> 6;
    const int quad = lane >> 4, l15 = lane & 15;
    const int wm = w >> 1, wn = w & 1;

    const int srow = w * 32 + (lane >> 2);
    const int kcol = (lane & 3) * 8;
    const _Float16* gBh = Bh + (size_t)(cbk * 128 + srow) * 512 + kcol;
    const _Float16* gBl = Bl + (size_t)(cbk * 128 + srow) * 512 + kcol;

    for (int g = blockIdx.y; g * 128 < count; g += gridDim.y) {
        __syncthreads();
        if (t < 128) {
            int p = g * 128 + t;
            rowidx[t] = (p < count) ? list[p] : list[0];
        }
        __syncthreads();

        f32x4 acc[4][4], acc2[4][4];
        const f32x4 z = {0.f, 0.f, 0.f, 0.f};
        #pragma unroll
        for (int i = 0; i < 4; ++i)
            #pragma unroll
            for (int j = 0; j < 4; ++j) { acc[i][j] = z; acc2[i][j] = z; }

        for (int ks = 0; ks < 16; ++ks) {
            const int ko = ks * 32;
            __syncthreads();
            gl_lds16(gBh + ko, &sBh[w * 1024]);
            gl_lds16(gBh + ko + (size_t)16 * 512, &sBh[w * 1024 + 512]);
            gl_lds16(gBl + ko, &sBl[w * 1024]);
            gl_lds16(gBl + ko + (size_t)16 * 512, &sBl[w * 1024 + 512]);
            #pragma unroll
            for (int i = 0; i < 2; ++i) {
                int idx = i * 256 + t;          // 0..511
                int row = idx >> 2, seg = (idx & 3) * 8;
                size_t src = (size_t)rowidx[row] * 512 + ko + seg;
                *(half8*)&sAh[row * 32 + seg] = *(const half8*)(Ah + src);
                *(half8*)&sAl[row * 32 + seg] = *(const half8*)(Al + src);
            }
            __syncthreads();
            half8 ah[4], al[4], bh[4], bl[4];
            #pragma unroll
            for (int i = 0; i < 4; ++i) {
                ah[i] = *(const half8*)&sAh[(wm * 64 + i * 16 + l15) * 32 + quad * 8];
                al[i] = *(const half8*)&sAl[(wm * 64 + i * 16 + l15) * 32 + quad * 8];
                bh[i] = *(const half8*)&sBh[(wn * 64 + i * 16 + l15) * 32 + quad * 8];
                bl[i] = *(const half8*)&sBl[(wn * 64 + i * 16 + l15) * 32 + quad * 8];
            }
            #pragma unroll
            for (int mi = 0; mi < 4; ++mi)
                #pragma unroll
                for (int ni = 0; ni < 4; ++ni) {
                    acc[mi][ni]  = __builtin_amdgcn_mfma_f32_16x16x32_f16(ah[mi], bh[ni], acc[mi][ni], 0, 0, 0);
                    acc2[mi][ni] = __builtin_amdgcn_mfma_f32_16x16x32_f16(ah[mi], bl[ni], acc2[mi][ni], 0, 0, 0);
                    acc2[mi][ni] = __builtin_amdgcn_mfma_f32_16x16x32_f16(al[mi], bh[ni], acc2[mi][ni], 0, 0, 0);
                }
        }

        #pragma unroll
        for (int mi = 0; mi < 4; ++mi)
            #pragma unroll
            for (int r = 0; r < 4; ++r) {
                float bv = -INFINITY;
                int bi = 0x7fffffff;
                #pragma unroll
                for (int ni = 0; ni < 4; ++ni) {
                    float v = acc[mi][ni][r] + acc2[mi][ni][r] * INV2048;
                    int col = cbk * 128 + wn * 64 + ni * 16 + l15;
                    if (v > bv || (v == bv && col < bi)) { bv = v; bi = col; }
                }
                #pragma unroll
                for (int o = 1; o < 16; o <<= 1) {
                    float ov = __shfl_xor(bv, o, 64);
                    int oi = __shfl_xor(bi, o, 64);
                    if (ov > bv || (ov == bv && oi < bi)) { bv = ov; bi = oi; }
                }
                if (l15 == 0) {
                    int row = wm * 64 + mi * 16 + quad * 4 + r;
                    pvs[row][wn] = bv; pis[row][wn] = bi;
                }
            }
        __syncthreads();
        if (t < 128 && g * 128 + t < count) {
            float v0 = pvs[t][0], v1 = pvs[t][1];
            int i0 = pis[t][0], i1 = pis[t][1];
            bool sw = (v1 > v0) || (v1 == v0 && i1 < i0);
            size_t o = (size_t)(g * 128 + t) * 32 + cbk;
            rpv[o] = sw ? v1 : v0;
            rpi[o] = sw ? i1 : i0;
        }
    }
}

__global__ __launch_bounds__(256) void k_fix(const float* __restrict__ rpv,
                                             const int* __restrict__ rpi,
                                             const int* __restrict__ list,
                                             const int* __restrict__ cnt,
                                             int* __restrict__ out) {
    int p = blockIdx.x * 256 + threadIdx.x;
    if (p >= *cnt) return;
    size_t base = (size_t)p * 32;
    float bv = -INFINITY;
    int bi = 0x7fffffff;
    #pragma unroll
    for (int j = 0; j < 32; ++j) {
        float v = rpv[base + j];
        int ci = rpi[base + j];
        if (v > bv || (v == bv && ci < bi)) { bv = v; bi = ci; }
    }
    out[list[p]] = bi;
}

extern "C" void kernel_launch(void* const* d_in, const int* in_sizes, int n_in,
                              void* d_out, int out_size, void* d_ws, size_t ws_size,
                              hipStream_t stream) {
    const float* x  = (const float*)d_in[0];   // [8,4096,1024]
    const float* rp = (const float*)d_in[1];   // [1024,512]
    const float* cb = (const float*)d_in[2];   // [4096,512]
    int* out = (int*)d_out;                    // [32768] int32

    char* ws = (char*)d_ws;
    _Float16* cn_h   = (_Float16*)(ws);
    _Float16* cn_l   = (_Float16*)(ws + ((size_t)4 << 20));
    _Float16* rpT_h  = (_Float16*)(ws + ((size_t)8 << 20));
    _Float16* rpT_l  = (_Float16*)(ws + ((size_t)9 << 20));
    _Float16* proj_h = (_Float16*)(ws + ((size_t)10 << 20));
    _Float16* proj_l = (_Float16*)(ws + ((size_t)42 << 20));
    float*    pv1    = (float*)   (ws + ((size_t)74 << 20));
    int*      pi1    = (int*)     (ws + ((size_t)78 << 20));
    float*    pv2    = (float*)   (ws + ((size_t)82 << 20));
    float*    rpv    = (float*)   (ws + ((size_t)86 << 20));
    int*      rpi    = (int*)     (ws + ((size_t)90 << 20));
    int*      list   = (int*)     (ws + ((size_t)94 << 20));
    int*      cnt    = (int*)     (ws + ((size_t)94 << 20) + (128 << 10));

    k_prep<<<4224, 256, 0, stream>>>(rp, rpT_h, rpT_l, cb, cn_h, cn_l, cnt);
    k_gemm1<<<1024, 256, 0, stream>>>(x, rpT_h, rpT_l, proj_h, proj_l);
    k_sim_h<<<dim3(16, 256), 256, 0, stream>>>(proj_h, cn_h, pv1, pi1, pv2);
    k_flag<<<128, 256, 0, stream>>>(pv1, pi1, pv2, out, list, cnt);
    k_sim_fix<<<dim3(32, 32), 256, 0, stream>>>(proj_h, proj_l, cn_h, cn_l, list, cnt, rpv, rpi);
    k_fix<<<128, 256, 0, stream>>>(rpv, rpi, list, cnt, out);
}

// Round 9
// 501.754 us; speedup vs baseline: 1.1746x; 1.0476x over previous
//
#include <hip/hip_runtime.h>
#include <math.h>

// B=8, N=4096, D=1024, E=512, C=4096.  M = 32768.
// Split-fp16 MFMA emulation of fp32 GEMM (a = h + l/2048, 3 MFMAs) for proj;
// hi-only fp16 pass for sim + deterministic margin rescue; contested rows
// recomputed exactly.
// R19: k_gemm1 X-path restructured. Old: X -> regs -> 32 split_f32 -> LDS
//      fp16 writes, all serialized between barriers (slot accounting: 12.3k
//      cyc/iter vs k_sim_h's 6.1k for +1.2k MFMA -> ~5k cyc of staging
//      serialization; MfmaUtil 26 + VALU 18 = both pipes idle 56%).
//      New: X staged as RAW FP32 via global_load_lds (issue-only, async,
//      like B), split done in the COMPUTE phase per-lane on read fragments
//      (VALU co-issues vs MFMA pipe, m114). Bit-identical split values and
//      MFMA order -> numerics unchanged. LDS 64KB (sX fp32 32K + sBh/sBl),
//      still 2 blocks/CU. fp32 A-tile bank plan: row's 16 segs in 2 planes
//      (even/odd), plane-local XOR j^(r&7); read 2x ds_read_b128 at
//      sidx=q8^(l15&7) -> 2 lanes/slot, conflict-free.
// R18 (kept): u32-key epilogue, [cbk][row] partials (WRITE 48->6MB),
//      (256,2), XCD chunk swizzle. k_sim_h at ~838 TF = structure ceiling.
//
// ws (MB): cn_h 0-4, cn_l 4-8, rpT_h 8-9, rpT_l 9-10, proj_h 10-42,
//          proj_l 42-74, pv1 74-78, pi1 78-82, pv2 82-86, rpv 86-90,
//          rpi 90-94, list 94-94.125, cnt @94.125

typedef _Float16 half8 __attribute__((ext_vector_type(8)));
typedef _Float16 half4 __attribute__((ext_vector_type(4)));
typedef float f32x4 __attribute__((ext_vector_type(4)));
typedef unsigned long long u64;
typedef unsigned int u32;

#define INV2048 (4.8828125e-4f)
#define MARGIN 0.034f

struct Split { _Float16 h, l; };

__device__ __forceinline__ Split split_f32(float v) {
    Split s;
    s.h = (_Float16)v;
    s.l = (_Float16)((v - (float)s.h) * 2048.0f);
    return s;
}

__device__ __forceinline__ void gl_lds16(const void* g, void* l) {
    __builtin_amdgcn_global_load_lds(
        (const __attribute__((address_space(1))) unsigned int*)g,
        (__attribute__((address_space(3))) unsigned int*)l, 16, 0, 0);
}

// monotone float->u32 key (finite inputs): order-preserving, key>0
__device__ __forceinline__ u32 fkey(float v) {
    u32 b = __float_as_uint(v);
    return b ^ ((u32)((int)b >> 31) | 0x80000000u);
}
__device__ __forceinline__ float fkeyinv(u32 u) {
    u32 m2 = (u32)((int)u >> 31);
    return __uint_as_float(u ^ ((~m2) | 0x80000000u));
}

// fused: blocks 0..127 transpose+split rp; blocks 128..4223 normalize+split cb
__global__ __launch_bounds__(256) void k_prep(const float* __restrict__ rp,
                                              _Float16* __restrict__ th,
                                              _Float16* __restrict__ tl,
                                              const float* __restrict__ cb,
                                              _Float16* __restrict__ ch,
                                              _Float16* __restrict__ cl,
                                              int* __restrict__ cnt) {
    const int t = threadIdx.x;
    if (blockIdx.x == 0 && t == 0) *cnt = 0;
    if (blockIdx.x < 128) {
        __shared__ float tile[64][65];
        const int k0 = (blockIdx.x & 15) * 64, n0 = (blockIdx.x >> 4) * 64;
        const int rr = t >> 6, cc = t & 63;
        #pragma unroll
        for (int i = 0; i < 16; ++i) {
            int r = i * 4 + rr;
            tile[r][cc] = rp[(size_t)(k0 + r) * 512 + n0 + cc];
        }
        __syncthreads();
        #pragma unroll
        for (int i = 0; i < 16; ++i) {
            int n = i * 4 + rr;
            Split s = split_f32(tile[cc][n]);
            size_t o = (size_t)(n0 + n) * 1024 + k0 + cc;
            th[o] = s.h;
            tl[o] = s.l;
        }
    } else {
        const int c = blockIdx.x - 128;
        const float* row = cb + (size_t)c * 512;
        float v0 = row[t];
        float v1 = row[t + 256];
        float ss = v0 * v0 + v1 * v1;
        #pragma unroll
        for (int o = 32; o > 0; o >>= 1) ss += __shfl_down(ss, o, 64);
        __shared__ float wsum[4];
        if ((t & 63) == 0) wsum[t >> 6] = ss;
        __syncthreads();
        float s = 1.0f / fmaxf(sqrtf(wsum[0] + wsum[1] + wsum[2] + wsum[3]), 1e-12f);
        Split s0 = split_f32(v0 * s);
        ch[(size_t)c * 512 + t] = s0.h;
        cl[(size_t)c * 512 + t] = s0.l;
        Split s1 = split_f32(v1 * s);
        ch[(size_t)c * 512 + t + 256] = s1.h;
        cl[(size_t)c * 512 + t + 256] = s1.l;
    }
}

// proj = x @ rp : M=32768, N=512, K=1024. split-fp16 3-MFMA (accurate).
// 1D grid + bijective XCD chunk swizzle. R19: X staged fp32 via gl_lds,
// split in compute phase.
__global__ __launch_bounds__(256, 2) void k_gemm1(const float* __restrict__ X,
                                                  const _Float16* __restrict__ Bh,
                                                  const _Float16* __restrict__ Bl,
                                                  _Float16* __restrict__ Ph,
                                                  _Float16* __restrict__ Pl) {
    __shared__ __align__(16) float sX[128 * 64];            // 32 KB fp32 A-tile
    __shared__ _Float16 sBh[128 * 64], sBl[128 * 64];       // 16 KB each
    const int t = threadIdx.x;
    const int bid = blockIdx.x;                 // 0..1023
    const int logical = (bid & 7) * 128 + (bid >> 3);   // bijective XCD chunking
    const int nb = logical & 3;   // 0..3
    const int mb = logical >> 2;  // 0..255
    const int lane = t & 63, w = t >> 6;
    const int quad = lane >> 4, l15 = lane & 15;
    const int wm = w >> 1, wn = w & 1;

    f32x4 acc[4][4], acc2[4][4];
    const f32x4 z = {0.f, 0.f, 0.f, 0.f};
    #pragma unroll
    for (int i = 0; i < 4; ++i)
        #pragma unroll
        for (int j = 0; j < 4; ++j) { acc[i][j] = z; acc2[i][j] = z; }

    // B staging (gl_lds, fp16): chunk = 8 rows x 128B; lane ell -> row
    // ell>>3, global seg (ell&7)^(ell>>3). Wave stages 32 rows of h and l.
    const int srow8 = lane >> 3;
    const int sseg = (lane & 7) ^ srow8;
    const _Float16* gBh = Bh + (size_t)(nb * 128 + w * 32 + srow8) * 1024 + sseg * 8;
    const _Float16* gBl = Bl + (size_t)(nb * 128 + w * 32 + srow8) * 1024 + sseg * 8;

    // X staging (gl_lds, fp32): chunk = 4 rows x 256B; lane ell -> row
    // ell>>4, lds slot sl = ell&15. Slot sl holds plane p = sl>>3,
    // plane-idx j = (sl&7)^(row&7), global seg = 2j+p (16B units).
    const int xcr = lane >> 4;        // 0..3 within chunk
    const int xsl = lane & 15;
    const float* gXw = X + (size_t)(mb * 128 + w * 32) * 1024;

    for (int ks = 0; ks < 16; ++ks) {
        const int ko = ks * 64;
        __syncthreads();
        #pragma unroll
        for (int c = 0; c < 4; ++c) {
            gl_lds16(gBh + ko + (size_t)(c * 8) * 1024, &sBh[(w * 32 + c * 8) * 64]);
            gl_lds16(gBl + ko + (size_t)(c * 8) * 1024, &sBl[(w * 32 + c * 8) * 64]);
        }
        #pragma unroll
        for (int c = 0; c < 8; ++c) {
            const int rr = c * 4 + xcr;                       // row within wave's 32
            const int gseg = ((((xsl & 7) ^ (rr & 7)) << 1) | (xsl >> 3));
            gl_lds16(gXw + (size_t)rr * 1024 + ko + gseg * 4,
                     &sX[(w * 32 + c * 4) * 64]);
        }
        __syncthreads();
        #pragma unroll
        for (int phase = 0; phase < 2; ++phase) {
            const int sidx = ((phase << 2) | quad) ^ (l15 & 7);   // 0..7
            half8 ah[4], al[4], bh[4], bl[4];
            #pragma unroll
            for (int i = 0; i < 4; ++i) {
                const float* xr = &sX[(wm * 64 + i * 16 + l15) * 64];
                f32x4 x0 = *(const f32x4*)&xr[sidx * 4];        // plane0: k lo 4
                f32x4 x1 = *(const f32x4*)&xr[32 + sidx * 4];   // plane1: k hi 4
                Split s0 = split_f32(x0[0]), s1 = split_f32(x0[1]);
                Split s2 = split_f32(x0[2]), s3 = split_f32(x0[3]);
                Split s4 = split_f32(x1[0]), s5 = split_f32(x1[1]);
                Split s6 = split_f32(x1[2]), s7 = split_f32(x1[3]);
                half8 hv, lv;
                hv[0] = s0.h; hv[1] = s1.h; hv[2] = s2.h; hv[3] = s3.h;
                hv[4] = s4.h; hv[5] = s5.h; hv[6] = s6.h; hv[7] = s7.h;
                lv[0] = s0.l; lv[1] = s1.l; lv[2] = s2.l; lv[3] = s3.l;
                lv[4] = s4.l; lv[5] = s5.l; lv[6] = s6.l; lv[7] = s7.l;
                ah[i] = hv;
                al[i] = lv;
            }
            #pragma unroll
            for (int i = 0; i < 4; ++i) {
                bh[i] = *(const half8*)&sBh[(wn * 64 + i * 16 + l15) * 64 + sidx * 8];
                bl[i] = *(const half8*)&sBl[(wn * 64 + i * 16 + l15) * 64 + sidx * 8];
            }
            #pragma unroll
            for (int mi = 0; mi < 4; ++mi)
                #pragma unroll
                for (int ni = 0; ni < 4; ++ni) {
                    acc[mi][ni]  = __builtin_amdgcn_mfma_f32_16x16x32_f16(ah[mi], bh[ni], acc[mi][ni], 0, 0, 0);
                    acc2[mi][ni] = __builtin_amdgcn_mfma_f32_16x16x32_f16(ah[mi], bl[ni], acc2[mi][ni], 0, 0, 0);
                    acc2[mi][ni] = __builtin_amdgcn_mfma_f32_16x16x32_f16(al[mi], bh[ni], acc2[mi][ni], 0, 0, 0);
                }
        }
    }
    #pragma unroll
    for (int mi = 0; mi < 4; ++mi)
        #pragma unroll
        for (int r = 0; r < 4; ++r) {
            int row = mb * 128 + wm * 64 + mi * 16 + quad * 4 + r;
            #pragma unroll
            for (int ni = 0; ni < 4; ++ni) {
                int col = nb * 128 + wn * 64 + ni * 16 + l15;
                float v = acc[mi][ni][r] + acc2[mi][ni][r] * INV2048;
                Split s = split_f32(v);
                Ph[(size_t)row * 512 + col] = s.h;
                Pl[(size_t)row * 512 + col] = s.l;
            }
        }
}

// PASS 1: hi-only sim. 128m x 256c tile, BK=64, 8 K-iters, 2 barriers/iter.
// Swizzle: LDS slot s (16B units, 8/row) of row r holds global seg s^(r&7).
// u32-key epilogue; partials stored [cbk][row] (full-line coalesced writes).
__global__ __launch_bounds__(256, 2) void k_sim_h(const _Float16* __restrict__ Ah,
                                                  const _Float16* __restrict__ Bh,
                                                  float* __restrict__ pv1,
                                                  int* __restrict__ pi1,
                                                  float* __restrict__ pv2) {
    __shared__ __align__(16) long long smem64[6144];   // 48 KB
    _Float16* sA = (_Float16*)smem64;                  // [128][64] halfs, 16 KB
    _Float16* sB = sA + 128 * 64;                      // [256][64] halfs, 32 KB
    u32* ek1 = (u32*)smem64;                           // [128][2] u32, 1 KB
    u32* ek2 = ek1 + 256;                              // [128][2] u32, 1 KB
    const int t = threadIdx.x;
    const int cbk = blockIdx.x;  // 0..15 (256-wide c-tiles)
    const int mb = blockIdx.y;   // 0..255
    const int lane = t & 63, w = t >> 6;
    const int quad = lane >> 4, l15 = lane & 15;
    const int wm = w >> 1, wn = w & 1;

    f32x4 acc[4][8];
    const f32x4 z = {0.f, 0.f, 0.f, 0.f};
    #pragma unroll
    for (int i = 0; i < 4; ++i)
        #pragma unroll
        for (int j = 0; j < 8; ++j) acc[i][j] = z;

    const int srow8 = lane >> 3;
    const int sseg = (lane & 7) ^ srow8;
    const _Float16* gA = Ah + (size_t)(mb * 128 + w * 32 + srow8) * 512 + sseg * 8;
    const _Float16* gB = Bh + (size_t)(cbk * 256 + w * 64 + srow8) * 512 + sseg * 8;

    for (int ks = 0; ks < 8; ++ks) {
        const int ko = ks * 64;
        __syncthreads();
        #pragma unroll
        for (int c = 0; c < 4; ++c)
            gl_lds16(gA + ko + (size_t)(c * 8) * 512, &sA[(w * 32 + c * 8) * 64]);
        #pragma unroll
        for (int c = 0; c < 8; ++c)
            gl_lds16(gB + ko + (size_t)(c * 8) * 512, &sB[(w * 64 + c * 8) * 64]);
        __syncthreads();
        #pragma unroll
        for (int phase = 0; phase < 2; ++phase) {
            const int slot = (((phase << 2) | quad) ^ (l15 & 7)) * 8;
            half8 a[4], b[8];
            #pragma unroll
            for (int i = 0; i < 4; ++i)
                a[i] = *(const half8*)&sA[(wm * 64 + i * 16 + l15) * 64 + slot];
            #pragma unroll
            for (int j = 0; j < 8; ++j)
                b[j] = *(const half8*)&sB[(wn * 128 + j * 16 + l15) * 64 + slot];
            #pragma unroll
            for (int mi = 0; mi < 4; ++mi)
                #pragma unroll
                for (int ni = 0; ni < 8; ++ni)
                    acc[mi][ni] = __builtin_amdgcn_mfma_f32_16x16x32_f16(a[mi], b[ni], acc[mi][ni], 0, 0, 0);
        }
    }

    __syncthreads();   // staging dead; reuse LDS as epilogue table
    // key = (fkey(v) & ~0xFFF) | (4095 - col): one u32, self-tiebreaking
    // (bigger value wins; on truncated-equal values, smaller col wins).
    const u32 colbase = 4095u - (u32)(cbk * 256 + wn * 128 + l15);
    #pragma unroll
    for (int mi = 0; mi < 4; ++mi)
        #pragma unroll
        for (int r = 0; r < 4; ++r) {
            int row = wm * 64 + mi * 16 + quad * 4 + r;
            u32 p1 = 0, p2 = 0;
            #pragma unroll
            for (int ni = 0; ni < 8; ++ni) {
                u32 k = (fkey(acc[mi][ni][r]) & 0xFFFFF000u) | (colbase - (u32)(ni * 16));
                u32 old1 = p1;
                u32 mn = old1 < k ? old1 : k;   // p2' = med3(p1, p2, k)
                p1 = old1 > k ? old1 : k;
                p2 = p2 > mn ? p2 : mn;
            }
            #pragma unroll
            for (int m = 1; m < 16; m <<= 1) {  // merge 16 lanes (same row)
                u32 q1 = __shfl_xor(p1, m, 64);
                u32 q2 = __shfl_xor(p2, m, 64);
                u32 m2 = p2 > q2 ? p2 : q2;
                u32 mn = p1 < q1 ? p1 : q1;
                p1 = p1 > q1 ? p1 : q1;
                p2 = m2 > mn ? m2 : mn;
            }
            if (l15 == 0) {
                ek1[row * 2 + wn] = p1;
                ek2[row * 2 + wn] = p2;
            }
        }
    __syncthreads();
    if (t < 128) {
        u32 a1 = ek1[t * 2], b1 = ek1[t * 2 + 1];
        u32 a2 = ek2[t * 2], b2 = ek2[t * 2 + 1];
        u32 top1 = a1 > b1 ? a1 : b1;
        u32 mn = a1 < b1 ? a1 : b1;
        u32 m2 = a2 > b2 ? a2 : b2;
        u32 top2 = m2 > mn ? m2 : mn;
        // [cbk][row] layout: contiguous full-line writes per block
        size_t o = (size_t)cbk * 32768 + (size_t)(mb * 128 + t);
        pv1[o] = fkeyinv(top1 & 0xFFFFF000u);
        pi1[o] = (int)(4095u - (top1 & 0xFFFu));
        pv2[o] = fkeyinv(top2 & 0xFFFFF000u);
    }
}

// reduce 16 c-tile partials; commit confident rows, queue contested ones
// partials are [cbk][row]: read pv[j*32768 + r] (coalesced per j)
__global__ __launch_bounds__(256) void k_flag(const float* __restrict__ pv1,
                                              const int* __restrict__ pi1,
                                              const float* __restrict__ pv2,
                                              int* __restrict__ out,
                                              int* __restrict__ list,
                                              int* __restrict__ cnt) {
    int r = blockIdx.x * 256 + threadIdx.x;
    if (r >= 32768) return;
    float v1 = pv1[r], v2 = pv2[r];
    int i1 = pi1[r];
    #pragma unroll
    for (int j = 1; j < 16; ++j) {
        float ov1 = pv1[(size_t)j * 32768 + r], ov2 = pv2[(size_t)j * 32768 + r];
        int oi1 = pi1[(size_t)j * 32768 + r];
        if (ov1 > v1 || (ov1 == v1 && oi1 < i1)) { v2 = fmaxf(v1, ov2); v1 = ov1; i1 = oi1; }
        else v2 = fmaxf(v2, ov1);
    }
    out[r] = i1;
    if (v1 - v2 < MARGIN) {
        int p = atomicAdd(cnt, 1);
        list[p] = r;
    }
}

// PASS 2: exact 3-MFMA sim on gathered contested rows
__global__ __launch_bounds__(256, 2) void k_sim_fix(const _Float16* __restrict__ Ah,
                                                    const _Float16* __restrict__ Al,
                                                    const _Float16* __restrict__ Bh,
                                                    const _Float16* __restrict__ Bl,
                                                    const int* __restrict__ list,
                                                    const int* __restrict__ cnt,
                                                    float* __restrict__ rpv,
                                                    int* __restrict__ rpi) {
    __shared__ _Float16 sAh[128 * 32], sAl[128 * 32], sBh[128 * 32], sBl[128 * 32];
    __shared__ int rowidx[128];
    __shared__ float pvs[128][2];
    __shared__ int   pis[128][2];
    const int count = *cnt;
    const int t = threadIdx.x;
    const int cbk = blockIdx.x;  // 0..31
    const int lane = t & 63, w = t >> 6;
    const int quad = lane >> 4, l15 = lane & 15;
    const int wm = w >> 1, wn = w & 1;

    const int srow = w * 32 + (lane >> 2);
    const int kcol = (lane & 3) * 8;
    const _Float16* gBh = Bh + (size_t)(cbk * 128 + srow) * 512 + kcol;
    const _Float16* gBl = Bl + (size_t)(cbk * 128 + srow) * 512 + kcol;

    for (int g = blockIdx.y; g * 128 < count; g += gridDim.y) {
        __syncthreads();
        if (t < 128) {
            int p = g * 128 + t;
            rowidx[t] = (p < count) ? list[p] : list[0];
        }
        __syncthreads();

        f32x4 acc[4][4], acc2[4][4];
        const f32x4 z = {0.f, 0.f, 0.f, 0.f};
        #pragma unroll
        for (int i = 0; i < 4; ++i)
            #pragma unroll
            for (int j = 0; j < 4; ++j) { acc[i][j] = z; acc2[i][j] = z; }

        for (int ks = 0; ks < 16; ++ks) {
            const int ko = ks * 32;
            __syncthreads();
            gl_lds16(gBh + ko, &sBh[w * 1024]);
            gl_lds16(gBh + ko + (size_t)16 * 512, &sBh[w * 1024 + 512]);
            gl_lds16(gBl + ko, &sBl[w * 1024]);
            gl_lds16(gBl + ko + (size_t)16 * 512, &sBl[w * 1024 + 512]);
            #pragma unroll
            for (int i = 0; i < 2; ++i) {
                int idx = i * 256 + t;          // 0..511
                int row = idx >> 2, seg = (idx & 3) * 8;
                size_t src = (size_t)rowidx[row] * 512 + ko + seg;
                *(half8*)&sAh[row * 32 + seg] = *(const half8*)(Ah + src);
                *(half8*)&sAl[row * 32 + seg] = *(const half8*)(Al + src);
            }
            __syncthreads();
            half8 ah[4], al[4], bh[4], bl[4];
            #pragma unroll
            for (int i = 0; i < 4; ++i) {
                ah[i] = *(const half8*)&sAh[(wm * 64 + i * 16 + l15) * 32 + quad * 8];
                al[i] = *(const half8*)&sAl[(wm * 64 + i * 16 + l15) * 32 + quad * 8];
                bh[i] = *(const half8*)&sBh[(wn * 64 + i * 16 + l15) * 32 + quad * 8];
                bl[i] = *(const half8*)&sBl[(wn * 64 + i * 16 + l15) * 32 + quad * 8];
            }
            #pragma unroll
            for (int mi = 0; mi < 4; ++mi)
                #pragma unroll
                for (int ni = 0; ni < 4; ++ni) {
                    acc[mi][ni]  = __builtin_amdgcn_mfma_f32_16x16x32_f16(ah[mi], bh[ni], acc[mi][ni], 0, 0, 0);
                    acc2[mi][ni] = __builtin_amdgcn_mfma_f32_16x16x32_f16(ah[mi], bl[ni], acc2[mi][ni], 0, 0, 0);
                    acc2[mi][ni] = __builtin_amdgcn_mfma_f32_16x16x32_f16(al[mi], bh[ni], acc2[mi][ni], 0, 0, 0);
                }
        }

        #pragma unroll
        for (int mi = 0; mi < 4; ++mi)
            #pragma unroll
            for (int r = 0; r < 4; ++r) {
                float bv = -INFINITY;
                int bi = 0x7fffffff;
                #pragma unroll
                for (int ni = 0; ni < 4; ++ni) {
                    float v = acc[mi][ni][r] + acc2[mi][ni][r] * INV2048;
                    int col = cbk * 128 + wn * 64 + ni * 16 + l15;
                    if (v > bv || (v == bv && col < bi)) { bv = v; bi = col; }
                }
                #pragma unroll
                for (int o = 1; o < 16; o <<= 1) {
                    float ov = __shfl_xor(bv, o, 64);
                    int oi = __shfl_xor(bi, o, 64);
                    if (ov > bv || (ov == bv && oi < bi)) { bv = ov; bi = oi; }
                }
                if (l15 == 0) {
                    int row = wm * 64 + mi * 16 + quad * 4 + r;
                    pvs[row][wn] = bv; pis[row][wn] = bi;
                }
            }
        __syncthreads();
        if (t < 128 && g * 128 + t < count) {
            float v0 = pvs[t][0], v1 = pvs[t][1];
            int i0 = pis[t][0], i1 = pis[t][1];
            bool sw = (v1 > v0) || (v1 == v0 && i1 < i0);
            size_t o = (size_t)(g * 128 + t) * 32 + cbk;
            rpv[o] = sw ? v1 : v0;
            rpi[o] = sw ? i1 : i0;
        }
    }
}

__global__ __launch_bounds__(256) void k_fix(const float* __restrict__ rpv,
                                             const int* __restrict__ rpi,
                                             const int* __restrict__ list,
                                             const int* __restrict__ cnt,
                                             int* __restrict__ out) {
    int p = blockIdx.x * 256 + threadIdx.x;
    if (p >= *cnt) return;
    size_t base = (size_t)p * 32;
    float bv = -INFINITY;
    int bi = 0x7fffffff;
    #pragma unroll
    for (int j = 0; j < 32; ++j) {
        float v = rpv[base + j];
        int ci = rpi[base + j];
        if (v > bv || (v == bv && ci < bi)) { bv = v; bi = ci; }
    }
    out[list[p]] = bi;
}

extern "C" void kernel_launch(void* const* d_in, const int* in_sizes, int n_in,
                              void* d_out, int out_size, void* d_ws, size_t ws_size,
                              hipStream_t stream) {
    const float* x  = (const float*)d_in[0];   // [8,4096,1024]
    const float* rp = (const float*)d_in[1];   // [1024,512]
    const float* cb = (const float*)d_in[2];   // [4096,512]
    int* out = (int*)d_out;                    // [32768] int32

    char* ws = (char*)d_ws;
    _Float16* cn_h   = (_Float16*)(ws);
    _Float16* cn_l   = (_Float16*)(ws + ((size_t)4 << 20));
    _Float16* rpT_h  = (_Float16*)(ws + ((size_t)8 << 20));
    _Float16* rpT_l  = (_Float16*)(ws + ((size_t)9 << 20));
    _Float16* proj_h = (_Float16*)(ws + ((size_t)10 << 20));
    _Float16* proj_l = (_Float16*)(ws + ((size_t)42 << 20));
    float*    pv1    = (float*)   (ws + ((size_t)74 << 20));
    int*      pi1    = (int*)     (ws + ((size_t)78 << 20));
    float*    pv2    = (float*)   (ws + ((size_t)82 << 20));
    float*    rpv    = (float*)   (ws + ((size_t)86 << 20));
    int*      rpi    = (int*)     (ws + ((size_t)90 << 20));
    int*      list   = (int*)     (ws + ((size_t)94 << 20));
    int*      cnt    = (int*)     (ws + ((size_t)94 << 20) + (128 << 10));

    k_prep<<<4224, 256, 0, stream>>>(rp, rpT_h, rpT_l, cb, cn_h, cn_l, cnt);
    k_gemm1<<<1024, 256, 0, stream>>>(x, rpT_h, rpT_l, proj_h, proj_l);
    k_sim_h<<<dim3(16, 256), 256, 0, stream>>>(proj_h, cn_h, pv1, pi1, pv2);
    k_flag<<<128, 256, 0, stream>>>(pv1, pi1, pv2, out, list, cnt);
    k_sim_fix<<<dim3(32, 32), 256, 0, stream>>>(proj_h, proj_l, cn_h, cn_l, list, cnt, rpv, rpi);
    k_fix<<<128, 256, 0, stream>>>(rpv, rpi, list, cnt, out);
}